// Round 5
// baseline (256.352 us; speedup 1.0000x reference)
//
#include <hip/hip_runtime.h>

// ISTFT: z[8][1026][2000] f32 (re 0..512, im 513..1025), window[1024] f32
// -> out[8][511744] f32
//
// Two-pass (default, needs 65.5MB d_ws):
//   memset(out); K1 transpose+c2r-pack -> Y'[b][t][512] cplx; K2 512-pt
//   Stockham inverse FFT/frame + window + atomic OLA; K3 normalize by wnorm.
// Fused fallback (ws too small): K2f reads z columns directly (L3-cached).

#define TFRAMES 2000
#define NB 8
#define LOUT 511744            // (2000-1)*256 + 1024 - 1024
#define PI_F 3.14159265358979323846f
#define YW_BYTES ((size_t)NB * TFRAMES * 512 * 2 * sizeof(float))

__global__ __launch_bounds__(256) void build_yprime(const float* __restrict__ z,
                                                    float* __restrict__ yw) {
  __shared__ float tA[32][33];
  __shared__ float tB[32][33];
  __shared__ float tC[32][33];
  __shared__ float tD[32][33];
  const int b  = blockIdx.z;
  const int k0 = blockIdx.y * 32;   // k tile base, k in [0,512)
  const int t0 = blockIdx.x * 32;   // t tile base
  const int tid = threadIdx.x;
  const int tt = tid & 31;          // t within tile
  const int rg = tid >> 5;          // row group 0..7
  const float* zb = z + (size_t)b * 1026 * TFRAMES;
  const int t = t0 + tt;
  const bool tin = (t < TFRAMES);
  // rows: A: k0+rr (Re X[k]) ; B: 512-k0-31+rr (Re X[512-k] reversed)
  //       C: 513+k0+rr (Im X[k]) ; D: 1025-k0-31+rr (Im X[512-k] reversed)
  for (int rr = rg; rr < 32; rr += 8) {
    tA[rr][tt] = tin ? zb[(size_t)(k0 + rr) * TFRAMES + t] : 0.f;
    tB[rr][tt] = tin ? zb[(size_t)(512 - k0 - 31 + rr) * TFRAMES + t] : 0.f;
    tC[rr][tt] = tin ? zb[(size_t)(513 + k0 + rr) * TFRAMES + t] : 0.f;
    tD[rr][tt] = tin ? zb[(size_t)(1025 - k0 - 31 + rr) * TFRAMES + t] : 0.f;
  }
  __syncthreads();
  const int kk = tid & 31;
  const int k = k0 + kk;
  float s, c;
  sincosf(PI_F * (float)k / 512.0f, &s, &c);   // e^{+2*pi*i*k/1024}
  for (int tr = rg; tr < 32; tr += 8) {
    int tcur = t0 + tr;
    if (tcur >= TFRAMES) break;
    float xr  = tA[kk][tr];           // Re X[k]
    float xr2 = tB[31 - kk][tr];      // Re X[512-k]
    float xi  = tC[kk][tr];           // Im X[k]
    float xi2 = tD[31 - kk][tr];      // Im X[512-k]
    if (k == 0) { xi = 0.f; xi2 = 0.f; }   // c2r ignores imag of DC/Nyquist
    // A = X[k] + conj(X[512-k]); B = (X[k] - conj(X[512-k])) * (c + i s)
    float Ar = xr + xr2;
    float Ai = xi - xi2;
    float Brp = xr - xr2;
    float Bip = xi + xi2;
    float Br = Brp * c - Bip * s;
    float Bi = Brp * s + Bip * c;
    // Y' = A + i*B
    float2 o = make_float2(Ar - Bi, Ai + Br);
    reinterpret_cast<float2*>(yw)[((size_t)b * TFRAMES + tcur) * 512 + k] = o;
  }
}

// Shared FFT+OLA tail: ar/ai/br/bi are 512-float LDS arrays, twc/tws 256.
__device__ __forceinline__ void fft_ola_tail(float* ar, float* ai, float* br,
                                             float* bi, const float* twc,
                                             const float* tws,
                                             const float* __restrict__ win,
                                             float* __restrict__ out, int b,
                                             int t, int tid) {
  // 9 Stockham radix-2 stages (inverse: positive-exponent twiddles)
  for (int sstage = 0; sstage < 9; ++sstage) {
    const int m = 1 << sstage;
    for (int u = 0; u < 4; ++u) {
      const int i = tid + (u << 6);           // butterfly index in [0,256)
      const float xar = ar[i],       xai = ai[i];
      const float xbr = ar[i + 256], xbi = ai[i + 256];
      const int h = i & ~(m - 1);
      const int idx = i + h;
      br[idx] = xar + xbr;
      bi[idx] = xai + xbi;
      const float tr = xar - xbr;
      const float ti = xai - xbi;
      const float c = twc[h], sn = tws[h];
      br[idx + m] = tr * c - ti * sn;
      bi[idx + m] = tr * sn + ti * c;
    }
    __syncthreads();
    float* tmp;
    tmp = ar; ar = br; br = tmp;
    tmp = ai; ai = bi; bi = tmp;
  }
  // ar/ai hold y[m]; x[2m] = Re y[m], x[2m+1] = Im y[m]; scale 1/1024
  const float scale = 1.0f / 1024.0f;
  const size_t obase = (size_t)b * LOUT;
  const int pbase = t * 256 - 512;           // trimmed output position of x[0]
  for (int i = tid; i < 512; i += 64) {
    const float v0 = ar[i] * scale * win[2 * i];
    const float v1 = ai[i] * scale * win[2 * i + 1];
    const int p0 = pbase + 2 * i;
    const int p1 = p0 + 1;
    if (p0 >= 0 && p0 < LOUT) atomicAdd(&out[obase + p0], v0);
    if (p1 >= 0 && p1 < LOUT) atomicAdd(&out[obase + p1], v1);
  }
}

__global__ __launch_bounds__(64) void ifft_ola(const float* __restrict__ yw,
                                               const float* __restrict__ win,
                                               float* __restrict__ out) {
  __shared__ float Xr[512];
  __shared__ float Xi[512];
  __shared__ float Yr[512];
  __shared__ float Yi[512];
  __shared__ float twc[256];
  __shared__ float tws[256];
  const int tid = threadIdx.x;
  const int frame = blockIdx.x;          // b*2000 + t
  const int b = frame / TFRAMES;
  const int t = frame - b * TFRAMES;
  for (int r = tid; r < 256; r += 64) {
    float s, c;
    sincosf((PI_F / 256.0f) * (float)r, &s, &c);   // e^{+2*pi*i*r/512}
    twc[r] = c; tws[r] = s;
  }
  const float2* src = reinterpret_cast<const float2*>(yw) + (size_t)frame * 512;
  for (int i = tid; i < 512; i += 64) {
    float2 v = src[i];
    Xr[i] = v.x; Xi[i] = v.y;
  }
  __syncthreads();
  fft_ola_tail(Xr, Xi, Yr, Yi, twc, tws, win, out, b, t, tid);
}

// Fused fallback: read z column directly (uncoalesced 4B loads; input fits L3)
__global__ __launch_bounds__(64) void ifft_ola_fused(const float* __restrict__ z,
                                                     const float* __restrict__ win,
                                                     float* __restrict__ out) {
  __shared__ float Zr[513];
  __shared__ float Zi[513];
  __shared__ float Xr[512];
  __shared__ float Xi[512];
  __shared__ float Yr[512];
  __shared__ float Yi[512];
  __shared__ float twc[256];
  __shared__ float tws[256];
  const int tid = threadIdx.x;
  const int frame = blockIdx.x;
  const int b = frame / TFRAMES;
  const int t = frame - b * TFRAMES;
  const float* zb = z + (size_t)b * 1026 * TFRAMES + t;
  for (int r = tid; r < 513; r += 64) {
    Zr[r] = zb[(size_t)r * TFRAMES];
    Zi[r] = zb[(size_t)(513 + r) * TFRAMES];
  }
  for (int r = tid; r < 256; r += 64) {
    float s, c;
    sincosf((PI_F / 256.0f) * (float)r, &s, &c);
    twc[r] = c; tws[r] = s;
  }
  __syncthreads();
  for (int k = tid; k < 512; k += 64) {
    float xr  = Zr[k];
    float xr2 = Zr[512 - k];
    float xi  = (k == 0) ? 0.f : Zi[k];
    float xi2 = (k == 0) ? 0.f : Zi[512 - k];
    float s, c;
    sincosf(PI_F * (float)k / 512.0f, &s, &c);
    float Ar = xr + xr2;
    float Ai = xi - xi2;
    float Brp = xr - xr2;
    float Bip = xi + xi2;
    float Br = Brp * c - Bip * s;
    float Bi = Brp * s + Bip * c;
    Xr[k] = Ar - Bi;
    Xi[k] = Ai + Br;
  }
  __syncthreads();
  fft_ola_tail(Xr, Xi, Yr, Yi, twc, tws, win, out, b, t, tid);
}

__global__ __launch_bounds__(256) void normalize_kernel(const float* __restrict__ win,
                                                        float* __restrict__ out) {
  const int total = NB * LOUT;
  for (int idx = blockIdx.x * blockDim.x + threadIdx.x; idx < total;
       idx += gridDim.x * blockDim.x) {
    const int q = idx % LOUT;          // position within batch row
    const int p = q + 512;             // untrimmed OLA position
    const int pm = p & 255;
    float wn = 0.f;
#pragma unroll
    for (int j = 0; j < 4; ++j) {
      const int o = pm + 256 * j;      // window offset candidate
      const int tt = (p - o) >> 8;     // frame index
      if (tt >= 0 && tt < TFRAMES) {
        const float w = win[o];
        wn += w * w;
      }
    }
    out[idx] = out[idx] / wn;
  }
}

extern "C" void kernel_launch(void* const* d_in, const int* in_sizes, int n_in,
                              void* d_out, int out_size, void* d_ws, size_t ws_size,
                              hipStream_t stream) {
  const float* z   = (const float*)d_in[0];
  const float* win = (const float*)d_in[1];
  float* out = (float*)d_out;

  hipMemsetAsync(d_out, 0, (size_t)out_size * sizeof(float), stream);

  if (ws_size >= YW_BYTES) {
    float* yw = (float*)d_ws;   // Y' : 16000 * 512 complex f32 = 65,536,000 B
    dim3 gA((TFRAMES + 31) / 32, 512 / 32, NB);   // 63 x 16 x 8
    build_yprime<<<gA, 256, 0, stream>>>(z, yw);
    ifft_ola<<<NB * TFRAMES, 64, 0, stream>>>(yw, win, out);
  } else {
    ifft_ola_fused<<<NB * TFRAMES, 64, 0, stream>>>(z, win, out);
  }

  normalize_kernel<<<2048, 256, 0, stream>>>(win, out);
}

// Round 9
// 156.261 us; speedup vs baseline: 1.6405x; 1.6405x over previous
//
#include <hip/hip_runtime.h>

// ISTFT: z[8][1026][2000] f32 (re 0..512, im 513..1025), window[1024] f32
// -> out[8][511744] f32
//
// Default pipeline (needs 65.5MB d_ws; confirmed available in round 5):
//   K1 build_yprime: transpose + c2r pre-pack -> Y'[b][t][512] cplx (d_ws)
//   K2 ifft8_frames: 512-pt radix-8^3 register FFT per frame (64 lanes x 8
//      cplx, 2 LDS shuffles, 3 single-wave barriers), window*(1/1024),
//      write windowed frame IN-PLACE over its own 4KB slot (no atomics).
//   K3 gather_norm: out[p] = sum of <=4 overlapping frame samples / wnorm(p).
// Fallback (ws too small): old fused ifft + atomic OLA + normalize.

#define TFRAMES 2000
#define NB 8
#define LOUT 511744            // (2000-1)*256 + 1024 - 1024
#define PI_F 3.14159265358979323846f
#define YW_BYTES ((size_t)NB * TFRAMES * 512 * 2 * sizeof(float))

// ---------------- K1: transpose + c2r pack (unchanged, measured-passing) ----
__global__ __launch_bounds__(256) void build_yprime(const float* __restrict__ z,
                                                    float* __restrict__ yw) {
  __shared__ float tA[32][33];
  __shared__ float tB[32][33];
  __shared__ float tC[32][33];
  __shared__ float tD[32][33];
  const int b  = blockIdx.z;
  const int k0 = blockIdx.y * 32;   // k tile base, k in [0,512)
  const int t0 = blockIdx.x * 32;   // t tile base
  const int tid = threadIdx.x;
  const int tt = tid & 31;          // t within tile
  const int rg = tid >> 5;          // row group 0..7
  const float* zb = z + (size_t)b * 1026 * TFRAMES;
  const int t = t0 + tt;
  const bool tin = (t < TFRAMES);
  for (int rr = rg; rr < 32; rr += 8) {
    tA[rr][tt] = tin ? zb[(size_t)(k0 + rr) * TFRAMES + t] : 0.f;
    tB[rr][tt] = tin ? zb[(size_t)(512 - k0 - 31 + rr) * TFRAMES + t] : 0.f;
    tC[rr][tt] = tin ? zb[(size_t)(513 + k0 + rr) * TFRAMES + t] : 0.f;
    tD[rr][tt] = tin ? zb[(size_t)(1025 - k0 - 31 + rr) * TFRAMES + t] : 0.f;
  }
  __syncthreads();
  const int kk = tid & 31;
  const int k = k0 + kk;
  float s, c;
  sincosf(PI_F * (float)k / 512.0f, &s, &c);   // e^{+2*pi*i*k/1024}
  for (int tr = rg; tr < 32; tr += 8) {
    int tcur = t0 + tr;
    if (tcur >= TFRAMES) break;
    float xr  = tA[kk][tr];           // Re X[k]
    float xr2 = tB[31 - kk][tr];      // Re X[512-k]
    float xi  = tC[kk][tr];           // Im X[k]
    float xi2 = tD[31 - kk][tr];      // Im X[512-k]
    if (k == 0) { xi = 0.f; xi2 = 0.f; }   // c2r ignores imag of DC/Nyquist
    float Ar = xr + xr2;
    float Ai = xi - xi2;
    float Brp = xr - xr2;
    float Bip = xi + xi2;
    float Br = Brp * c - Bip * s;
    float Bi = Brp * s + Bip * c;
    float2 o = make_float2(Ar - Bi, Ai + Br);   // Y' = A + i*B
    reinterpret_cast<float2*>(yw)[((size_t)b * TFRAMES + tcur) * 512 + k] = o;
  }
}

// ---------------- complex helpers -------------------------------------------
__device__ __forceinline__ float2 cadd(float2 a, float2 b) {
  return make_float2(a.x + b.x, a.y + b.y);
}
__device__ __forceinline__ float2 csub(float2 a, float2 b) {
  return make_float2(a.x - b.x, a.y - b.y);
}
__device__ __forceinline__ float2 cmul(float2 a, float2 b) {
  return make_float2(a.x * b.x - a.y * b.y, a.x * b.y + a.y * b.x);
}
__device__ __forceinline__ float2 cmuli(float2 a) {     // * (+i)
  return make_float2(-a.y, a.x);
}

// 8-point DFT, positive exponent: y[j] = sum_k x[k] e^{2*pi*i*j*k/8}
__device__ __forceinline__ void dft8(const float2* x, float2* y) {
  const float S = 0.70710678118654752440f;
  float2 t0 = cadd(x[0], x[4]), t1 = csub(x[0], x[4]);
  float2 t2 = cadd(x[2], x[6]), t3 = csub(x[2], x[6]);
  float2 t4 = cadd(x[1], x[5]), t5 = csub(x[1], x[5]);
  float2 t6 = cadd(x[3], x[7]), t7 = csub(x[3], x[7]);
  float2 it3 = cmuli(t3);
  float2 E0 = cadd(t0, t2), E2 = csub(t0, t2);
  float2 E1 = cadd(t1, it3), E3 = csub(t1, it3);
  float2 it7 = cmuli(t7);
  float2 O0 = cadd(t4, t6), O2 = csub(t4, t6);
  float2 O1 = cadd(t5, it7), O3 = csub(t5, it7);
  float2 w1O = make_float2(S * (O1.x - O1.y), S * (O1.x + O1.y));   // *W8^1
  float2 w2O = cmuli(O2);                                            // *W8^2
  float2 w3O = make_float2(-S * (O3.x + O3.y), S * (O3.x - O3.y));   // *W8^3
  y[0] = cadd(E0, O0); y[4] = csub(E0, O0);
  y[1] = cadd(E1, w1O); y[5] = csub(E1, w1O);
  y[2] = cadd(E2, w2O); y[6] = csub(E2, w2O);
  y[3] = cadd(E3, w3O); y[7] = csub(E3, w3O);
}

// ---------------- K2: radix-8^3 register FFT + window, in-place -------------
// Decomposition: k = k1 + 8*k2 + 64*k3, j = j1 + 8*j2 + 64*j3.
// Stage1 (over k3, thread tid = k1+8*k2) -> twiddle W512^{j1*tid}
// Stage2 (over k2, thread k1 = tid&7, j1 = tid>>3) -> twiddle W64^{j2*k1}
// Stage3 (over k1, thread j1 = tid&7, j2 = tid>>3) -> y[tid + 64*j3]
__global__ __launch_bounds__(64) void ifft8_frames(float* __restrict__ ws,
                                                   const float* __restrict__ win) {
  __shared__ float2 sh[584];            // 64 rows x 9 (pad) = 576 used
  const int tid = threadIdx.x;
  const int frame = blockIdx.x;         // b*2000 + t
  float2* fr = reinterpret_cast<float2*>(ws) + (size_t)frame * 512;
  const float2* win2 = reinterpret_cast<const float2*>(win);

  float2 x[8], y[8];
#pragma unroll
  for (int j = 0; j < 8; ++j) x[j] = fr[tid + 64 * j];   // coalesced

  // ---- stage 1: DFT8 over k3 ----
  dft8(x, y);
  {
    float s1, c1;
    sincosf((2.0f * PI_F / 512.0f) * (float)tid, &s1, &c1);
    float2 w = make_float2(c1, s1);     // W512^{tid}
    float2 cur = w;
    y[1] = cmul(y[1], cur);
#pragma unroll
    for (int j = 2; j < 8; ++j) { cur = cmul(cur, w); y[j] = cmul(y[j], cur); }
  }
  const int row1 = (tid & 7) * 8 + (tid >> 3);     // k1*8 + k2
#pragma unroll
  for (int j = 0; j < 8; ++j) sh[row1 * 9 + j] = y[j];
  __syncthreads();

  // ---- stage 2: DFT8 over k2 ----
  {
    const int k1 = tid & 7, j1 = tid >> 3;
#pragma unroll
    for (int k2 = 0; k2 < 8; ++k2) x[k2] = sh[(k1 * 8 + k2) * 9 + j1];
    dft8(x, y);
    float s1, c1;
    sincosf((2.0f * PI_F / 64.0f) * (float)k1, &s1, &c1);
    float2 w = make_float2(c1, s1);     // W64^{k1}
    float2 cur = w;
    y[1] = cmul(y[1], cur);
#pragma unroll
    for (int j = 2; j < 8; ++j) { cur = cmul(cur, w); y[j] = cmul(y[j], cur); }
    __syncthreads();                    // all stage-2 reads done
#pragma unroll
    for (int j2 = 0; j2 < 8; ++j2) sh[(j1 * 8 + j2) * 9 + k1] = y[j2];
  }
  __syncthreads();

  // ---- stage 3: DFT8 over k1 ----
#pragma unroll
  for (int k1 = 0; k1 < 8; ++k1) x[k1] = sh[row1 * 9 + k1];  // row1 = (tid&7)*8+(tid>>3) = j1*8+j2
  dft8(x, y);

  // y[j3] = Y[tid + 64*j3]; time pair (x[2m], x[2m+1]) = (Re, Im) * win * 1/1024
  const float scale = 1.0f / 1024.0f;
#pragma unroll
  for (int j3 = 0; j3 < 8; ++j3) {
    const int m = tid + 64 * j3;
    const float2 wv = win2[m];
    fr[m] = make_float2(y[j3].x * wv.x * scale, y[j3].y * wv.y * scale);
  }
}

// ---------------- K3: gather 4 overlapping frames + normalize ---------------
__global__ __launch_bounds__(256) void gather_norm(const float* __restrict__ frames,
                                                   const float* __restrict__ win,
                                                   float* __restrict__ out) {
  const int b = blockIdx.y;
  const int q = blockIdx.x * 256 + threadIdx.x;  // grid.x*256 == LOUT exactly
  const int p = q + 512;                         // untrimmed position
  const int tb = p >> 8;
  const int pm = p & 255;
  const float* fb = frames + (size_t)b * TFRAMES * 1024;
  float acc = 0.f, wn = 0.f;
#pragma unroll
  for (int j = 0; j < 4; ++j) {
    const int t = tb - j;
    if (t >= 0 && t < TFRAMES) {
      const int o = pm + (j << 8);
      acc += fb[(size_t)t * 1024 + o];
      const float w = win[o];
      wn += w * w;
    }
  }
  out[(size_t)b * LOUT + q] = acc / wn;
}

// ---------------- fallback path (old, measured-passing) ---------------------
__device__ __forceinline__ void fft_ola_tail(float* ar, float* ai, float* br,
                                             float* bi, const float* twc,
                                             const float* tws,
                                             const float* __restrict__ win,
                                             float* __restrict__ out, int b,
                                             int t, int tid) {
  for (int sstage = 0; sstage < 9; ++sstage) {
    const int m = 1 << sstage;
    for (int u = 0; u < 4; ++u) {
      const int i = tid + (u << 6);
      const float xar = ar[i],       xai = ai[i];
      const float xbr = ar[i + 256], xbi = ai[i + 256];
      const int h = i & ~(m - 1);
      const int idx = i + h;
      br[idx] = xar + xbr;
      bi[idx] = xai + xbi;
      const float tr = xar - xbr;
      const float ti = xai - xbi;
      const float c = twc[h], sn = tws[h];
      br[idx + m] = tr * c - ti * sn;
      bi[idx + m] = tr * sn + ti * c;
    }
    __syncthreads();
    float* tmp;
    tmp = ar; ar = br; br = tmp;
    tmp = ai; ai = bi; bi = tmp;
  }
  const float scale = 1.0f / 1024.0f;
  const size_t obase = (size_t)b * LOUT;
  const int pbase = t * 256 - 512;
  for (int i = tid; i < 512; i += 64) {
    const float v0 = ar[i] * scale * win[2 * i];
    const float v1 = ai[i] * scale * win[2 * i + 1];
    const int p0 = pbase + 2 * i;
    const int p1 = p0 + 1;
    if (p0 >= 0 && p0 < LOUT) atomicAdd(&out[obase + p0], v0);
    if (p1 >= 0 && p1 < LOUT) atomicAdd(&out[obase + p1], v1);
  }
}

__global__ __launch_bounds__(64) void ifft_ola_fused(const float* __restrict__ z,
                                                     const float* __restrict__ win,
                                                     float* __restrict__ out) {
  __shared__ float Zr[513];
  __shared__ float Zi[513];
  __shared__ float Xr[512];
  __shared__ float Xi[512];
  __shared__ float Yr[512];
  __shared__ float Yi[512];
  __shared__ float twc[256];
  __shared__ float tws[256];
  const int tid = threadIdx.x;
  const int frame = blockIdx.x;
  const int b = frame / TFRAMES;
  const int t = frame - b * TFRAMES;
  const float* zb = z + (size_t)b * 1026 * TFRAMES + t;
  for (int r = tid; r < 513; r += 64) {
    Zr[r] = zb[(size_t)r * TFRAMES];
    Zi[r] = zb[(size_t)(513 + r) * TFRAMES];
  }
  for (int r = tid; r < 256; r += 64) {
    float s, c;
    sincosf((PI_F / 256.0f) * (float)r, &s, &c);
    twc[r] = c; tws[r] = s;
  }
  __syncthreads();
  for (int k = tid; k < 512; k += 64) {
    float xr  = Zr[k];
    float xr2 = Zr[512 - k];
    float xi  = (k == 0) ? 0.f : Zi[k];
    float xi2 = (k == 0) ? 0.f : Zi[512 - k];
    float s, c;
    sincosf(PI_F * (float)k / 512.0f, &s, &c);
    float Ar = xr + xr2;
    float Ai = xi - xi2;
    float Brp = xr - xr2;
    float Bip = xi + xi2;
    float Br = Brp * c - Bip * s;
    float Bi = Brp * s + Bip * c;
    Xr[k] = Ar - Bi;
    Xi[k] = Ai + Br;
  }
  __syncthreads();
  fft_ola_tail(Xr, Xi, Yr, Yi, twc, tws, win, out, b, t, tid);
}

__global__ __launch_bounds__(256) void normalize_kernel(const float* __restrict__ win,
                                                        float* __restrict__ out) {
  const int total = NB * LOUT;
  for (int idx = blockIdx.x * blockDim.x + threadIdx.x; idx < total;
       idx += gridDim.x * blockDim.x) {
    const int q = idx % LOUT;
    const int p = q + 512;
    const int pm = p & 255;
    float wn = 0.f;
#pragma unroll
    for (int j = 0; j < 4; ++j) {
      const int o = pm + 256 * j;
      const int tt = (p - o) >> 8;
      if (tt >= 0 && tt < TFRAMES) {
        const float w = win[o];
        wn += w * w;
      }
    }
    out[idx] = out[idx] / wn;
  }
}

// ---------------- launch ----------------------------------------------------
extern "C" void kernel_launch(void* const* d_in, const int* in_sizes, int n_in,
                              void* d_out, int out_size, void* d_ws, size_t ws_size,
                              hipStream_t stream) {
  const float* z   = (const float*)d_in[0];
  const float* win = (const float*)d_in[1];
  float* out = (float*)d_out;

  if (ws_size >= YW_BYTES) {
    float* yw = (float*)d_ws;   // 65,536,000 B; reused in-place for frames
    dim3 gA((TFRAMES + 31) / 32, 512 / 32, NB);        // 63 x 16 x 8
    build_yprime<<<gA, 256, 0, stream>>>(z, yw);
    ifft8_frames<<<NB * TFRAMES, 64, 0, stream>>>(yw, win);
    dim3 gG(LOUT / 256, NB);                           // 1999 x 8, exact
    gather_norm<<<gG, 256, 0, stream>>>(yw, win, out);
  } else {
    hipMemsetAsync(d_out, 0, (size_t)out_size * sizeof(float), stream);
    ifft_ola_fused<<<NB * TFRAMES, 64, 0, stream>>>(z, win, out);
    normalize_kernel<<<2048, 256, 0, stream>>>(win, out);
  }
}

// Round 10
// 144.589 us; speedup vs baseline: 1.7730x; 1.0807x over previous
//
#include <hip/hip_runtime.h>

// ISTFT: z[8][1026][2000] f32 (re 0..512, im 513..1025), window[1024] f32
// -> out[8][511744] f32
//
// Default pipeline (needs 65.5MB d_ws for the frames buffer):
//   KA pack_fft_frames: per block, stage 8 z-columns (1026x8) coalesced into
//      LDS; each of 8 waves packs the c2r half-spectrum of one frame DIRECTLY
//      into its FFT input registers (Y' never touches memory), runs the
//      512-pt radix-8^3 register FFT (scratch aliased over staging),
//      windows*(1/1024), writes the frame to d_ws.
//   KB gather_norm: out[p] = sum of <=4 overlapping frame samples / wnorm(p).
// Fallback (ws too small): fused ifft + atomic OLA + normalize (measured ok).

#define TFRAMES 2000
#define NB 8
#define LOUT 511744            // (2000-1)*256 + 1024 - 1024
#define PI_F 3.14159265358979323846f
#define YW_BYTES ((size_t)NB * TFRAMES * 512 * 2 * sizeof(float))
#define NT 8                   // frames per block in KA

// ---------------- complex helpers -------------------------------------------
__device__ __forceinline__ float2 cadd(float2 a, float2 b) {
  return make_float2(a.x + b.x, a.y + b.y);
}
__device__ __forceinline__ float2 csub(float2 a, float2 b) {
  return make_float2(a.x - b.x, a.y - b.y);
}
__device__ __forceinline__ float2 cmul(float2 a, float2 b) {
  return make_float2(a.x * b.x - a.y * b.y, a.x * b.y + a.y * b.x);
}
__device__ __forceinline__ float2 cmuli(float2 a) {     // * (+i)
  return make_float2(-a.y, a.x);
}

// 8-point DFT, positive exponent: y[j] = sum_k x[k] e^{2*pi*i*j*k/8}
__device__ __forceinline__ void dft8(const float2* x, float2* y) {
  const float S = 0.70710678118654752440f;
  float2 t0 = cadd(x[0], x[4]), t1 = csub(x[0], x[4]);
  float2 t2 = cadd(x[2], x[6]), t3 = csub(x[2], x[6]);
  float2 t4 = cadd(x[1], x[5]), t5 = csub(x[1], x[5]);
  float2 t6 = cadd(x[3], x[7]), t7 = csub(x[3], x[7]);
  float2 it3 = cmuli(t3);
  float2 E0 = cadd(t0, t2), E2 = csub(t0, t2);
  float2 E1 = cadd(t1, it3), E3 = csub(t1, it3);
  float2 it7 = cmuli(t7);
  float2 O0 = cadd(t4, t6), O2 = csub(t4, t6);
  float2 O1 = cadd(t5, it7), O3 = csub(t5, it7);
  float2 w1O = make_float2(S * (O1.x - O1.y), S * (O1.x + O1.y));   // *W8^1
  float2 w2O = cmuli(O2);                                            // *W8^2
  float2 w3O = make_float2(-S * (O3.x + O3.y), S * (O3.x - O3.y));   // *W8^3
  y[0] = cadd(E0, O0); y[4] = csub(E0, O0);
  y[1] = cadd(E1, w1O); y[5] = csub(E1, w1O);
  y[2] = cadd(E2, w2O); y[6] = csub(E2, w2O);
  y[3] = cadd(E3, w3O); y[7] = csub(E3, w3O);
}

// ---------------- KA: fused stage + c2r pack + radix-8^3 FFT + window -------
// Per block: 8 frames (t0..t0+7), 8 waves, wave w owns frame t0+w.
// Pack identity (k in [0,512), X = half-spectrum, Y' = packed c2c input):
//   Y'[k] = (X[k]+conj(X[512-k])) + i*e^{i*pi*k/512}*(X[k]-conj(X[512-k]))
// Pack iteration q yields exactly x[q] = Y'[64q + lane] (FFT stage-1 input).
// FFT decomposition: k = k1+8k2+64k3, j = j1+8j2+64j3 (verified round 9).
__global__ __launch_bounds__(512, 4) void pack_fft_frames(
    const float* __restrict__ z, const float* __restrict__ win,
    float* __restrict__ frames) {
  // staging [NT][1026] floats (32832 B) and per-wave FFT scratch [8][584]
  // float2 (37376 B) are time-disjoint -> alias one buffer.
  __shared__ __attribute__((aligned(16))) unsigned char smem[37376];
  float*  sz      = reinterpret_cast<float*>(smem);
  float2* scratch = reinterpret_cast<float2*>(smem);
  const int tid  = threadIdx.x;
  const int lane = tid & 63;
  const int wave = tid >> 6;                 // 0..7
  const int b    = blockIdx.y;
  const int t0   = blockIdx.x * NT;
  const float* zb = z + (size_t)b * 1026 * TFRAMES;

  // ---- stage: rows 0..1025 x 8 t's; thread -> (r = pass*128 + tid/4,
  //      tq = (tid&3)*2), float2 load (lanes 0-3 cover 32B contiguous) ----
#pragma unroll
  for (int pass = 0; pass < 9; ++pass) {
    const int r = pass * 128 + (tid >> 2);
    if (r < 1026) {
      const int tq = (tid & 3) * 2;
      const float2 v = *reinterpret_cast<const float2*>(
          zb + (size_t)r * TFRAMES + (t0 + tq));
      sz[tq * 1026 + r]       = v.x;
      sz[(tq + 1) * 1026 + r] = v.y;
    }
  }
  __syncthreads();

  // ---- pack frame tf=wave into registers x[0..7] ----
  const float* szt = sz + wave * 1026;
  float2 x[8], y[8];
  float s0, c0;
  sincosf(PI_F * (float)lane / 512.0f, &s0, &c0);
  const float2 w0 = make_float2(c0, s0);     // e^{i*pi*lane/512}
  const float2 W16[8] = {                    // e^{i*pi*q/8}
    { 1.f, 0.f},
    { 0.92387953251128675613f, 0.38268343236508977173f},
    { 0.70710678118654752440f, 0.70710678118654752440f},
    { 0.38268343236508977173f, 0.92387953251128675613f},
    { 0.f, 1.f},
    {-0.38268343236508977173f, 0.92387953251128675613f},
    {-0.70710678118654752440f, 0.70710678118654752440f},
    {-0.92387953251128675613f, 0.38268343236508977173f}};
#pragma unroll
  for (int q = 0; q < 8; ++q) {
    const int k = q * 64 + lane;
    const float xr  = szt[k];                // Re X[k]
    const float xr2 = szt[512 - k];          // Re X[512-k]
    float xi  = szt[513 + k];                // Im X[k]
    float xi2 = szt[1025 - k];               // Im X[512-k]
    if (k == 0) { xi = 0.f; xi2 = 0.f; }     // c2r ignores imag of DC/Nyquist
    const float2 tw = cmul(W16[q], w0);      // e^{i*pi*k/512}
    const float Ar = xr + xr2,  Ai = xi - xi2;
    const float Brp = xr - xr2, Bip = xi + xi2;
    const float Br = Brp * tw.x - Bip * tw.y;
    const float Bi = Brp * tw.y + Bip * tw.x;
    x[q] = make_float2(Ar - Bi, Ai + Br);    // Y'[k] = A + i*B
  }
  __syncthreads();   // all waves done reading staging; scratch may now alias

  float2* sh = scratch + wave * 584;         // wave-private, 9-padded rows

  // ---- stage 1: DFT8 over k3, twiddle W512^{j1*tid} (w0^2 = W512^lane) ----
  dft8(x, y);
  {
    const float2 w1 = cmul(w0, w0);          // e^{2*pi*i*lane/512}
    float2 cur = w1;
    y[1] = cmul(y[1], cur);
#pragma unroll
    for (int j = 2; j < 8; ++j) { cur = cmul(cur, w1); y[j] = cmul(y[j], cur); }
  }
  const int row1 = (lane & 7) * 8 + (lane >> 3);     // k1*8 + k2
#pragma unroll
  for (int j = 0; j < 8; ++j) sh[row1 * 9 + j] = y[j];
  __syncthreads();

  // ---- stage 2: DFT8 over k2, twiddle W64^{j2*k1} ----
  {
    const int k1 = lane & 7, j1 = lane >> 3;
#pragma unroll
    for (int k2 = 0; k2 < 8; ++k2) x[k2] = sh[(k1 * 8 + k2) * 9 + j1];
    dft8(x, y);
    float s1, c1;
    sincosf((2.0f * PI_F / 64.0f) * (float)k1, &s1, &c1);
    const float2 w = make_float2(c1, s1);    // W64^{k1}
    float2 cur = w;
    y[1] = cmul(y[1], cur);
#pragma unroll
    for (int j = 2; j < 8; ++j) { cur = cmul(cur, w); y[j] = cmul(y[j], cur); }
    __syncthreads();                         // all stage-2 reads done
#pragma unroll
    for (int j2 = 0; j2 < 8; ++j2) sh[(j1 * 8 + j2) * 9 + k1] = y[j2];
  }
  __syncthreads();

  // ---- stage 3: DFT8 over k1; y[j3] = Y[lane + 64*j3] ----
#pragma unroll
  for (int k1 = 0; k1 < 8; ++k1) x[k1] = sh[row1 * 9 + k1];  // row1 = j1*8+j2
  dft8(x, y);

  // time pair (x[2m], x[2m+1]) = (Re, Im) of Y[m]; window * 1/1024; store
  const float scale = 1.0f / 1024.0f;
  const int t = t0 + wave;
  float2* fr = reinterpret_cast<float2*>(frames) +
               ((size_t)b * TFRAMES + t) * 512;
  const float2* win2 = reinterpret_cast<const float2*>(win);
#pragma unroll
  for (int j3 = 0; j3 < 8; ++j3) {
    const int m = lane + 64 * j3;
    const float2 wv = win2[m];
    fr[m] = make_float2(y[j3].x * wv.x * scale, y[j3].y * wv.y * scale);
  }
}

// ---------------- KB: gather 4 overlapping frames + normalize ---------------
__global__ __launch_bounds__(256) void gather_norm(const float* __restrict__ frames,
                                                   const float* __restrict__ win,
                                                   float* __restrict__ out) {
  const int b = blockIdx.y;
  const int q = blockIdx.x * 256 + threadIdx.x;  // grid.x*256 == LOUT exactly
  const int p = q + 512;                         // untrimmed position
  const int tb = p >> 8;
  const int pm = p & 255;
  const float* fb = frames + (size_t)b * TFRAMES * 1024;
  float acc = 0.f, wn = 0.f;
#pragma unroll
  for (int j = 0; j < 4; ++j) {
    const int t = tb - j;
    if (t >= 0 && t < TFRAMES) {
      const int o = pm + (j << 8);
      acc += fb[(size_t)t * 1024 + o];
      const float w = win[o];
      wn += w * w;
    }
  }
  out[(size_t)b * LOUT + q] = acc / wn;
}

// ---------------- fallback path (measured-passing in round 5) ---------------
__device__ __forceinline__ void fft_ola_tail(float* ar, float* ai, float* br,
                                             float* bi, const float* twc,
                                             const float* tws,
                                             const float* __restrict__ win,
                                             float* __restrict__ out, int b,
                                             int t, int tid) {
  for (int sstage = 0; sstage < 9; ++sstage) {
    const int m = 1 << sstage;
    for (int u = 0; u < 4; ++u) {
      const int i = tid + (u << 6);
      const float xar = ar[i],       xai = ai[i];
      const float xbr = ar[i + 256], xbi = ai[i + 256];
      const int h = i & ~(m - 1);
      const int idx = i + h;
      br[idx] = xar + xbr;
      bi[idx] = xai + xbi;
      const float tr = xar - xbr;
      const float ti = xai - xbi;
      const float c = twc[h], sn = tws[h];
      br[idx + m] = tr * c - ti * sn;
      bi[idx + m] = tr * sn + ti * c;
    }
    __syncthreads();
    float* tmp;
    tmp = ar; ar = br; br = tmp;
    tmp = ai; ai = bi; bi = tmp;
  }
  const float scale = 1.0f / 1024.0f;
  const size_t obase = (size_t)b * LOUT;
  const int pbase = t * 256 - 512;
  for (int i = tid; i < 512; i += 64) {
    const float v0 = ar[i] * scale * win[2 * i];
    const float v1 = ai[i] * scale * win[2 * i + 1];
    const int p0 = pbase + 2 * i;
    const int p1 = p0 + 1;
    if (p0 >= 0 && p0 < LOUT) atomicAdd(&out[obase + p0], v0);
    if (p1 >= 0 && p1 < LOUT) atomicAdd(&out[obase + p1], v1);
  }
}

__global__ __launch_bounds__(64) void ifft_ola_fused(const float* __restrict__ z,
                                                     const float* __restrict__ win,
                                                     float* __restrict__ out) {
  __shared__ float Zr[513];
  __shared__ float Zi[513];
  __shared__ float Xr[512];
  __shared__ float Xi[512];
  __shared__ float Yr[512];
  __shared__ float Yi[512];
  __shared__ float twc[256];
  __shared__ float tws[256];
  const int tid = threadIdx.x;
  const int frame = blockIdx.x;
  const int b = frame / TFRAMES;
  const int t = frame - b * TFRAMES;
  const float* zb = z + (size_t)b * 1026 * TFRAMES + t;
  for (int r = tid; r < 513; r += 64) {
    Zr[r] = zb[(size_t)r * TFRAMES];
    Zi[r] = zb[(size_t)(513 + r) * TFRAMES];
  }
  for (int r = tid; r < 256; r += 64) {
    float s, c;
    sincosf((PI_F / 256.0f) * (float)r, &s, &c);
    twc[r] = c; tws[r] = s;
  }
  __syncthreads();
  for (int k = tid; k < 512; k += 64) {
    float xr  = Zr[k];
    float xr2 = Zr[512 - k];
    float xi  = (k == 0) ? 0.f : Zi[k];
    float xi2 = (k == 0) ? 0.f : Zi[512 - k];
    float s, c;
    sincosf(PI_F * (float)k / 512.0f, &s, &c);
    float Ar = xr + xr2;
    float Ai = xi - xi2;
    float Brp = xr - xr2;
    float Bip = xi + xi2;
    float Br = Brp * c - Bip * s;
    float Bi = Brp * s + Bip * c;
    Xr[k] = Ar - Bi;
    Xi[k] = Ai + Br;
  }
  __syncthreads();
  fft_ola_tail(Xr, Xi, Yr, Yi, twc, tws, win, out, b, t, tid);
}

__global__ __launch_bounds__(256) void normalize_kernel(const float* __restrict__ win,
                                                        float* __restrict__ out) {
  const int total = NB * LOUT;
  for (int idx = blockIdx.x * blockDim.x + threadIdx.x; idx < total;
       idx += gridDim.x * blockDim.x) {
    const int q = idx % LOUT;
    const int p = q + 512;
    const int pm = p & 255;
    float wn = 0.f;
#pragma unroll
    for (int j = 0; j < 4; ++j) {
      const int o = pm + 256 * j;
      const int tt = (p - o) >> 8;
      if (tt >= 0 && tt < TFRAMES) {
        const float w = win[o];
        wn += w * w;
      }
    }
    out[idx] = out[idx] / wn;
  }
}

// ---------------- launch ----------------------------------------------------
extern "C" void kernel_launch(void* const* d_in, const int* in_sizes, int n_in,
                              void* d_out, int out_size, void* d_ws, size_t ws_size,
                              hipStream_t stream) {
  const float* z   = (const float*)d_in[0];
  const float* win = (const float*)d_in[1];
  float* out = (float*)d_out;

  if (ws_size >= YW_BYTES) {
    float* frames = (float*)d_ws;   // 16000 frames x 1024 f32 = 65,536,000 B
    dim3 gA(TFRAMES / NT, NB);                         // 250 x 8
    pack_fft_frames<<<gA, 512, 0, stream>>>(z, win, frames);
    dim3 gG(LOUT / 256, NB);                           // 1999 x 8, exact
    gather_norm<<<gG, 256, 0, stream>>>(frames, win, out);
  } else {
    hipMemsetAsync(d_out, 0, (size_t)out_size * sizeof(float), stream);
    ifft_ola_fused<<<NB * TFRAMES, 64, 0, stream>>>(z, win, out);
    normalize_kernel<<<2048, 256, 0, stream>>>(win, out);
  }
}